// Round 2
// baseline (242.482 us; speedup 1.0000x reference)
//
#include <hip/hip_runtime.h>

// Problem constants
#define NSEQ 64
#define LL   256
#define DD   256
#define HH   8
#define HDIM 32

typedef short short8  __attribute__((ext_vector_type(8)));
typedef short short4v __attribute__((ext_vector_type(4)));
typedef float float4v __attribute__((ext_vector_type(4)));

#define MFMA16(a,b,c) __builtin_amdgcn_mfma_f32_16x16x32_bf16((a),(b),(c),0,0,0)

__device__ __forceinline__ float4v zero4() {
  float4v z;
  z[0] = 0.f; z[1] = 0.f; z[2] = 0.f; z[3] = 0.f;
  return z;
}

__device__ __forceinline__ short f2b(float f) {
  unsigned u = __float_as_uint(f);
  u = (u + 0x7fffu + ((u >> 16) & 1u)) >> 16;   // RNE
  return (short)u;
}

__device__ __forceinline__ short8 cvt8(const float* p) {
  float4 a = *(const float4*)p;
  float4 b = *(const float4*)(p + 4);
  short8 r;
  r[0] = f2b(a.x); r[1] = f2b(a.y); r[2] = f2b(a.z); r[3] = f2b(a.w);
  r[4] = f2b(b.x); r[5] = f2b(b.y); r[6] = f2b(b.z); r[7] = f2b(b.w);
  return r;
}

// ---- workspace layout (bytes); total ~34.5 MB ----
#define WT_OFF   0                           // 4 x 256x256 bf16 (Wq^T,Wk^T,Wv^T,Wo^T)
#define PB_OFF   (4*65536*2)                 // 8 x 256x256 f32 pair bias [h][i][j]
#define Q_OFF    (PB_OFF + 8*65536*4)        // 16384x256 bf16 [row][ch]
#define K_OFF    (Q_OFF  + 16384*256*2)      // 16384x256 bf16 [row][ch]
#define VT_OFF   (K_OFF  + 16384*256*2)      // [n][h][hd][j] bf16
#define O_OFF    (VT_OFF + 16384*256*2)      // 16384x256 bf16 attn out [row][ch]

// ============================================================================
// K1: weight transpose+cvt  AND  pair-bias GEMM pb[h][i][j] = pair@Wpb + bpb
// grid: 256 (pb) + 1024 (weights) = 1280 blocks x 256 thr
// ============================================================================
__global__ __launch_bounds__(256) void k1_prep(
    const float* __restrict__ pair, const float* __restrict__ Wq,
    const float* __restrict__ Wk,   const float* __restrict__ Wv,
    const float* __restrict__ Wpb,  const float* __restrict__ bpb,
    const float* __restrict__ Wo,   char* __restrict__ ws)
{
  __shared__ short ldsWt[16 * 136];   // Wpb^T bf16, rows 8..15 zero, ld=136 (pad)
  int bx = blockIdx.x, tid = threadIdx.x;
  if (bx < 256) {
    float* pbw = (float*)(ws + PB_OFF);
    for (int i = tid; i < 16 * 136; i += 256) ldsWt[i] = 0;
    __syncthreads();
    {
      // Wpb is (128,8) row-major: flat = k*8 + n ; each thread converts 4
      float4 wv4 = *(const float4*)&Wpb[tid * 4];
      int kk = (tid * 4) >> 3, n0 = (tid * 4) & 7;
      ldsWt[(n0 + 0) * 136 + kk] = f2b(wv4.x);
      ldsWt[(n0 + 1) * 136 + kk] = f2b(wv4.y);
      ldsWt[(n0 + 2) * 136 + kk] = f2b(wv4.z);
      ldsWt[(n0 + 3) * 136 + kk] = f2b(wv4.w);
    }
    __syncthreads();
    int w = tid >> 6, l = tid & 63, q = l >> 4, c = l & 15;
    int base = bx * 256 + w * 64;          // position index (i*256+j)
    float bias = bpb[c & 7];
    short8 bf[4];
#pragma unroll
    for (int ks = 0; ks < 4; ks++)
      bf[ks] = *(const short8*)&ldsWt[c * 136 + ks * 32 + q * 8];
    float4v acc[4];
#pragma unroll
    for (int mt = 0; mt < 4; mt++) acc[mt] = zero4();
#pragma unroll
    for (int ks = 0; ks < 4; ks++) {
#pragma unroll
      for (int mt = 0; mt < 4; mt++) {
        short8 af = cvt8(&pair[(base + mt * 16 + c) * 128 + ks * 32 + q * 8]);
        acc[mt] = MFMA16(af, bf[ks], acc[mt]);
      }
    }
    if (c < 8) {                           // C cols 0..7 are the 8 heads
#pragma unroll
      for (int mt = 0; mt < 4; mt++) {
        float4 o;
        o.x = acc[mt][0] + bias; o.y = acc[mt][1] + bias;
        o.z = acc[mt][2] + bias; o.w = acc[mt][3] + bias;
        // rows (regs) are 4 consecutive positions -> contiguous dwordx4
        *(float4*)&pbw[c * 65536 + base + mt * 16 + q * 4] = o;
      }
    }
  } else {
    // weight transpose: wt[n][k] = W[k][n], bf16
    int b2 = bx - 256;
    int mat = b2 >> 8, r = b2 & 255;
    const float* W = (mat == 0) ? Wq : (mat == 1) ? Wk : (mat == 2) ? Wv : Wo;
    short* wt = (short*)(ws + WT_OFF) + mat * 65536;
    wt[tid * 256 + r] = f2b(W[r * 256 + tid]);
  }
}

// ============================================================================
// K2: QKV projection. grid 512 x 256thr; wave = 16 rows x 128 cols, 3 matrices
// ============================================================================
__global__ __launch_bounds__(256) void k2_qkv(
    const float* __restrict__ msa, const float* __restrict__ bq,
    const float* __restrict__ bk,  const float* __restrict__ bv,
    char* __restrict__ ws)
{
  int bx = blockIdx.x, tid = threadIdx.x;
  int w = tid >> 6, l = tid & 63, q = l >> 4, c = l & 15;
  int r0  = bx * 32 + (w & 1) * 16;     // global row (n*256+i)
  int ch0 = (w >> 1) * 128;             // output channel base
  const short* wtb = (const short*)(ws + WT_OFF);
  short8 afr[8];
#pragma unroll
  for (int ks = 0; ks < 8; ks++)
    afr[ks] = cvt8(&msa[(r0 + c) * 256 + ks * 32 + q * 8]);
#pragma unroll 1
  for (int m = 0; m < 3; m++) {
    const short* wt = wtb + m * 65536;
    const float* bp = (m == 0) ? bq : (m == 1) ? bk : bv;
    float4v acc[8];
#pragma unroll
    for (int nt = 0; nt < 8; nt++) acc[nt] = zero4();
#pragma unroll
    for (int ks = 0; ks < 8; ks++) {
#pragma unroll
      for (int nt = 0; nt < 8; nt++) {
        short8 bf = *(const short8*)&wt[(ch0 + nt * 16 + c) * 256 + ks * 32 + q * 8];
        acc[nt] = MFMA16(afr[ks], bf, acc[nt]);
      }
    }
    if (m < 2) {
      short* dst = (short*)(ws + (m == 0 ? Q_OFF : K_OFF));
#pragma unroll
      for (int nt = 0; nt < 8; nt++) {
        float bb = bp[ch0 + nt * 16 + c];
#pragma unroll
        for (int r = 0; r < 4; r++)
          dst[(r0 + q * 4 + r) * 256 + ch0 + nt * 16 + c] = f2b(acc[nt][r] + bb);
      }
    } else {
      short* vt = (short*)(ws + VT_OFF);
      int n = r0 >> 8;
      int j0 = (r0 & 255) + q * 4;     // 4 consecutive j (regs) -> b64 store
#pragma unroll
      for (int nt = 0; nt < 8; nt++) {
        int ch = ch0 + nt * 16 + c;
        float bb = bp[ch];
        short4v s4;
#pragma unroll
        for (int r = 0; r < 4; r++) s4[r] = f2b(acc[nt][r] + bb);
        *(short4v*)&vt[((n * HH + (ch >> 5)) * HDIM + (ch & 31)) * 256 + j0] = s4;
      }
    }
  }
}

// ============================================================================
// K3: attention per (n,h). 512 blocks x 256 thr. No barriers (wave-private P).
// ============================================================================
__global__ __launch_bounds__(256) void k3_attn(char* __restrict__ ws)
{
  __shared__ short P[64 * 264];          // 64 rows (4 waves x16), ld=264 pad
  int bx = blockIdx.x, tid = threadIdx.x;
  int n = bx >> 3, h = bx & 7;
  int w = tid >> 6, l = tid & 63, q = l >> 4, c = l & 15;
  const short* qs  = (const short*)(ws + Q_OFF);
  const short* kks = (const short*)(ws + K_OFF);
  const short* vt  = (const short*)(ws + VT_OFF);
  const float* pbp = (const float*)(ws + PB_OFF) + h * 65536;
  short* os = (short*)(ws + O_OFF);
  const float scale = 0.17677669529663687f;   // 1/sqrt(32)
#pragma unroll 1
  for (int qq = 0; qq < 4; qq++) {
    int i0 = qq * 64 + w * 16;           // this wave's 16 query rows
    short8 aq = *(const short8*)&qs[(n * 256 + i0 + c) * 256 + h * 32 + q * 8];
    float4v s[16];
#pragma unroll
    for (int jt = 0; jt < 16; jt++) {
      short8 bk8 = *(const short8*)&kks[(n * 256 + jt * 16 + c) * 256 + h * 32 + q * 8];
      s[jt] = MFMA16(aq, bk8, zero4());
    }
    // scale + pair bias (C layout: col=jt*16+c, row=q*4+r)
#pragma unroll
    for (int jt = 0; jt < 16; jt++) {
#pragma unroll
      for (int r = 0; r < 4; r++) {
        float pbv = pbp[(i0 + q * 4 + r) * 256 + jt * 16 + c];
        s[jt][r] = __builtin_fmaf(s[jt][r], scale, pbv);
      }
    }
    // softmax per row: in-lane over jt, then xor-shuffle over the 16 col lanes
    float inv[4];
#pragma unroll
    for (int r = 0; r < 4; r++) {
      float m = s[0][r];
#pragma unroll
      for (int jt = 1; jt < 16; jt++) m = fmaxf(m, s[jt][r]);
      m = fmaxf(m, __shfl_xor(m, 1, 64));
      m = fmaxf(m, __shfl_xor(m, 2, 64));
      m = fmaxf(m, __shfl_xor(m, 4, 64));
      m = fmaxf(m, __shfl_xor(m, 8, 64));
      float rs = 0.f;
#pragma unroll
      for (int jt = 0; jt < 16; jt++) {
        float p = __expf(s[jt][r] - m);
        s[jt][r] = p;
        rs += p;
      }
      rs += __shfl_xor(rs, 1, 64);
      rs += __shfl_xor(rs, 2, 64);
      rs += __shfl_xor(rs, 4, 64);
      rs += __shfl_xor(rs, 8, 64);
      inv[r] = 1.f / rs;
    }
    // P -> LDS (C-layout -> A-layout transform)
#pragma unroll
    for (int jt = 0; jt < 16; jt++)
#pragma unroll
      for (int r = 0; r < 4; r++)
        P[(w * 16 + q * 4 + r) * 264 + jt * 16 + c] = f2b(s[jt][r]);
    // O = P @ V   (A from own P rows, B from vt[n][h][hd][j])
    float4v o0 = zero4(), o1 = zero4();
#pragma unroll
    for (int kk = 0; kk < 8; kk++) {
      short8 ap = *(const short8*)&P[(w * 16 + c) * 264 + kk * 32 + q * 8];
      short8 b0 = *(const short8*)&vt[((n * HH + h) * HDIM + c) * 256 + kk * 32 + q * 8];
      short8 b1 = *(const short8*)&vt[((n * HH + h) * HDIM + 16 + c) * 256 + kk * 32 + q * 8];
      o0 = MFMA16(ap, b0, o0);
      o1 = MFMA16(ap, b1, o1);
    }
#pragma unroll
    for (int r = 0; r < 4; r++) {
      os[(n * 256 + i0 + q * 4 + r) * 256 + h * 32 + c]      = f2b(o0[r] * inv[r]);
      os[(n * 256 + i0 + q * 4 + r) * 256 + h * 32 + 16 + c] = f2b(o1[r] * inv[r]);
    }
  }
}

// ============================================================================
// K4: out-proj + bias + residual + LayerNorm. grid 256 x 256 thr (wave=16 rows)
// ============================================================================
__global__ __launch_bounds__(256) void k4_out(
    const float* __restrict__ msa, const float* __restrict__ bo,
    const float* __restrict__ gamma, const float* __restrict__ beta,
    const char* __restrict__ ws, float* __restrict__ out)
{
  int bx = blockIdx.x, tid = threadIdx.x;
  int w = tid >> 6, l = tid & 63, q = l >> 4, c = l & 15;
  int r0 = bx * 64 + w * 16;
  const short* osrc = (const short*)(ws + O_OFF);
  const short* wto  = (const short*)(ws + WT_OFF) + 3 * 65536;
  short8 afr[8];
#pragma unroll
  for (int ks = 0; ks < 8; ks++)
    afr[ks] = *(const short8*)&osrc[(r0 + c) * 256 + ks * 32 + q * 8];
  float4v acc[16];
#pragma unroll
  for (int nt = 0; nt < 16; nt++) acc[nt] = zero4();
#pragma unroll
  for (int ks = 0; ks < 8; ks++)
#pragma unroll
    for (int nt = 0; nt < 16; nt++) {
      short8 bf = *(const short8*)&wto[(nt * 16 + c) * 256 + ks * 32 + q * 8];
      acc[nt] = MFMA16(afr[ks], bf, acc[nt]);
    }
  float s1[4] = {0, 0, 0, 0}, s2[4] = {0, 0, 0, 0};
#pragma unroll
  for (int nt = 0; nt < 16; nt++) {
    float bb = bo[nt * 16 + c];
#pragma unroll
    for (int r = 0; r < 4; r++) {
      float x = acc[nt][r] + bb + msa[(r0 + q * 4 + r) * 256 + nt * 16 + c];
      acc[nt][r] = x;
      s1[r] += x;
      s2[r] = __builtin_fmaf(x, x, s2[r]);
    }
  }
  float mu[4], rsd[4];
#pragma unroll
  for (int r = 0; r < 4; r++) {
    float a = s1[r], b = s2[r];
    a += __shfl_xor(a, 1, 64); b += __shfl_xor(b, 1, 64);
    a += __shfl_xor(a, 2, 64); b += __shfl_xor(b, 2, 64);
    a += __shfl_xor(a, 4, 64); b += __shfl_xor(b, 4, 64);
    a += __shfl_xor(a, 8, 64); b += __shfl_xor(b, 8, 64);
    float m = a * (1.f / 256.f);
    float v = __builtin_fmaf(-m, m, b * (1.f / 256.f));
    mu[r] = m;
    rsd[r] = rsqrtf(v + 1e-5f);
  }
#pragma unroll
  for (int nt = 0; nt < 16; nt++) {
    float g = gamma[nt * 16 + c], bt = beta[nt * 16 + c];
#pragma unroll
    for (int r = 0; r < 4; r++)
      out[(r0 + q * 4 + r) * 256 + nt * 16 + c] =
          (acc[nt][r] - mu[r]) * rsd[r] * g + bt;
  }
}

extern "C" void kernel_launch(void* const* d_in, const int* in_sizes, int n_in,
                              void* d_out, int out_size, void* d_ws, size_t ws_size,
                              hipStream_t stream)
{
  const float* msa   = (const float*)d_in[0];
  const float* pair  = (const float*)d_in[1];
  const float* Wq    = (const float*)d_in[2];
  const float* bq    = (const float*)d_in[3];
  const float* Wk    = (const float*)d_in[4];
  const float* bk    = (const float*)d_in[5];
  const float* Wv    = (const float*)d_in[6];
  const float* bv    = (const float*)d_in[7];
  const float* Wpb   = (const float*)d_in[8];
  const float* bpb   = (const float*)d_in[9];
  const float* Wo    = (const float*)d_in[10];
  const float* bo    = (const float*)d_in[11];
  const float* gamma = (const float*)d_in[12];
  const float* beta  = (const float*)d_in[13];
  char* ws = (char*)d_ws;
  float* out = (float*)d_out;

  hipLaunchKernelGGL(k1_prep, dim3(1280), dim3(256), 0, stream,
                     pair, Wq, Wk, Wv, Wpb, bpb, Wo, ws);
  hipLaunchKernelGGL(k2_qkv, dim3(512), dim3(256), 0, stream,
                     msa, bq, bk, bv, ws);
  hipLaunchKernelGGL(k3_attn, dim3(512), dim3(256), 0, stream, ws);
  hipLaunchKernelGGL(k4_out, dim3(256), dim3(256), 0, stream,
                     msa, bo, gamma, beta, ws, out);
}

// Round 3
// 187.478 us; speedup vs baseline: 1.2934x; 1.2934x over previous
//
#include <hip/hip_runtime.h>

// Problem constants
#define NSEQ 64
#define LL   256
#define DD   256
#define HH   8
#define HDIM 32

typedef short short8  __attribute__((ext_vector_type(8)));
typedef short short4v __attribute__((ext_vector_type(4)));
typedef float float4v __attribute__((ext_vector_type(4)));

#define MFMA16(a,b,c) __builtin_amdgcn_mfma_f32_16x16x32_bf16((a),(b),(c),0,0,0)

__device__ __forceinline__ float4v zero4() {
  float4v z;
  z[0] = 0.f; z[1] = 0.f; z[2] = 0.f; z[3] = 0.f;
  return z;
}

__device__ __forceinline__ short f2b(float f) {
  unsigned u = __float_as_uint(f);
  u = (u + 0x7fffu + ((u >> 16) & 1u)) >> 16;   // RNE
  return (short)u;
}

__device__ __forceinline__ short8 cvt8(const float* p) {
  float4 a = *(const float4*)p;
  float4 b = *(const float4*)(p + 4);
  short8 r;
  r[0] = f2b(a.x); r[1] = f2b(a.y); r[2] = f2b(a.z); r[3] = f2b(a.w);
  r[4] = f2b(b.x); r[5] = f2b(b.y); r[6] = f2b(b.z); r[7] = f2b(b.w);
  return r;
}

// async global->LDS, 16B per lane. LDS dest must be wave-uniform-base + lane*16.
__device__ __forceinline__ void ld_lds16(const void* g, void* l) {
  __builtin_amdgcn_global_load_lds(
      (const __attribute__((address_space(1))) unsigned int*)g,
      (__attribute__((address_space(3))) unsigned int*)l, 16, 0, 0);
}
#define WAIT_VM0() __builtin_amdgcn_s_waitcnt(0x0F70)   // vmcnt(0) only

// ---- workspace layout (bytes); total ~34.5 MB (MSA16 and O share) ----
#define WT_OFF    0                            // 4 x 256x256 bf16 (Wq^T,Wk^T,Wv^T,Wo^T) [ch][k]
#define PB_OFF    (4*65536*2)                  // 8 x 256x256 f32 pair bias [h][i][j]
#define Q_OFF     (PB_OFF + 8*65536*4)         // 16384x256 bf16 [row][ch]
#define K_OFF     (Q_OFF  + 16384*256*2)       // 16384x256 bf16 [row][ch]
#define VT_OFF    (K_OFF  + 16384*256*2)       // [n][h][hd][j] bf16
#define MSA16_OFF (VT_OFF + 16384*256*2)       // 16384x256 bf16 (dead after k2)
#define O_OFF     MSA16_OFF                    // k3 output overlays MSA16

// ============================================================================
// K1: pb GEMM (256) + weight transpose (1024) + msa->bf16 (512) = 1792 blocks
// ============================================================================
__global__ __launch_bounds__(256) void k1_prep(
    const float* __restrict__ msa,  const float* __restrict__ pair,
    const float* __restrict__ Wq,   const float* __restrict__ Wk,
    const float* __restrict__ Wv,   const float* __restrict__ Wpb,
    const float* __restrict__ bpb,  const float* __restrict__ Wo,
    char* __restrict__ ws)
{
  __shared__ short ldsWt[16 * 136];   // Wpb^T bf16, rows 8..15 zero, ld=136 (pad)
  int bx = blockIdx.x, tid = threadIdx.x;
  if (bx < 256) {
    float* pbw = (float*)(ws + PB_OFF);
    for (int i = tid; i < 16 * 136; i += 256) ldsWt[i] = 0;
    __syncthreads();
    {
      float4 wv4 = *(const float4*)&Wpb[tid * 4];
      int kk = (tid * 4) >> 3, n0 = (tid * 4) & 7;
      ldsWt[(n0 + 0) * 136 + kk] = f2b(wv4.x);
      ldsWt[(n0 + 1) * 136 + kk] = f2b(wv4.y);
      ldsWt[(n0 + 2) * 136 + kk] = f2b(wv4.z);
      ldsWt[(n0 + 3) * 136 + kk] = f2b(wv4.w);
    }
    __syncthreads();
    int w = tid >> 6, l = tid & 63, q = l >> 4, c = l & 15;
    int base = bx * 256 + w * 64;
    float bias = bpb[c & 7];
    short8 bf[4];
#pragma unroll
    for (int ks = 0; ks < 4; ks++)
      bf[ks] = *(const short8*)&ldsWt[c * 136 + ks * 32 + q * 8];
    float4v acc[4];
#pragma unroll
    for (int mt = 0; mt < 4; mt++) acc[mt] = zero4();
#pragma unroll
    for (int ks = 0; ks < 4; ks++) {
#pragma unroll
      for (int mt = 0; mt < 4; mt++) {
        short8 af = cvt8(&pair[(base + mt * 16 + c) * 128 + ks * 32 + q * 8]);
        acc[mt] = MFMA16(af, bf[ks], acc[mt]);
      }
    }
    if (c < 8) {
#pragma unroll
      for (int mt = 0; mt < 4; mt++) {
        float4 o;
        o.x = acc[mt][0] + bias; o.y = acc[mt][1] + bias;
        o.z = acc[mt][2] + bias; o.w = acc[mt][3] + bias;
        *(float4*)&pbw[c * 65536 + base + mt * 16 + q * 4] = o;
      }
    }
  } else if (bx < 1280) {
    // weight transpose: wt[n][k] = W[k][n], bf16
    int b2 = bx - 256;
    int mat = b2 >> 8, r = b2 & 255;
    const float* W = (mat == 0) ? Wq : (mat == 1) ? Wk : (mat == 2) ? Wv : Wo;
    short* wt = (short*)(ws + WT_OFF) + mat * 65536;
    wt[tid * 256 + r] = f2b(W[r * 256 + tid]);
  } else {
    // msa -> bf16 row-major
    int b3 = bx - 1280;                 // 0..511, 32 rows each
    const float* src = msa + b3 * 8192;
    short* dst = (short*)(ws + MSA16_OFF) + b3 * 8192;
#pragma unroll
    for (int i = 0; i < 8; i++) {
      int idx = i * 1024 + tid * 4;
      float4 v = *(const float4*)&src[idx];
      short4v s;
      s[0] = f2b(v.x); s[1] = f2b(v.y); s[2] = f2b(v.z); s[3] = f2b(v.w);
      *(short4v*)&dst[idx] = s;
    }
  }
}

// ============================================================================
// K2: QKV as one GEMM C[16384x768] = msa16 @ [Wq^T;Wk^T;Wv^T], 128x128 tiles,
// BK=128 (2 K-steps), LDS-staged via global_load_lds + XOR swizzle.
// grid 768 = 128 row-tiles x 6 col-tiles. 64KB LDS -> 2 blocks/CU.
// ============================================================================
__global__ __launch_bounds__(256) void k2_qkv(
    const float* __restrict__ bq, const float* __restrict__ bk,
    const float* __restrict__ bv, char* __restrict__ ws)
{
  __shared__ __align__(16) short lsA[128 * 128];
  __shared__ __align__(16) short lsB[128 * 128];
  int bx = blockIdx.x, tid = threadIdx.x;
  int rt = bx & 127, ct = bx >> 7;       // row-tile, col-tile
  int m = ct >> 1, cb = (ct & 1) * 128;  // matrix, ch base within matrix
  int R0 = rt * 128;
  const short* msa16 = (const short*)(ws + MSA16_OFF);
  const short* wt = (const short*)(ws + WT_OFF) + m * 65536;
  int w = tid >> 6, l = tid & 63, q = l >> 4, c = l & 15;
  int WR = (w & 1) * 64, WC = (w >> 1) * 64;
  float4v acc[4][4];
#pragma unroll
  for (int mt = 0; mt < 4; mt++)
#pragma unroll
    for (int nt = 0; nt < 4; nt++) acc[mt][nt] = zero4();

#pragma unroll 1
  for (int kk = 0; kk < 2; kk++) {
    if (kk) __syncthreads();             // all waves done reading LDS
    // stage A (128 rows x 128 k) and B (128 ch x 128 k), swizzled: pos = kc ^ (r&7)
#pragma unroll
    for (int i = 0; i < 8; i++) {
      int ci = i * 256 + tid;
      int r = ci >> 4, pos = ci & 15;
      int kc = pos ^ (r & 7);
      ld_lds16(&msa16[(R0 + r) * 256 + kk * 128 + kc * 8], &lsA[ci * 8]);
    }
#pragma unroll
    for (int i = 0; i < 8; i++) {
      int ci = i * 256 + tid;
      int r = ci >> 4, pos = ci & 15;
      int kc = pos ^ (r & 7);
      ld_lds16(&wt[(cb + r) * 256 + kk * 128 + kc * 8], &lsB[ci * 8]);
    }
    WAIT_VM0();
    __syncthreads();
#pragma unroll
    for (int ks = 0; ks < 4; ks++) {
      short8 af[4], bf[4];
#pragma unroll
      for (int mt = 0; mt < 4; mt++) {
        int r = WR + mt * 16 + c;
        int phys = (ks * 4 + q) ^ (r & 7);
        af[mt] = *(const short8*)&lsA[r * 128 + phys * 8];
      }
#pragma unroll
      for (int nt = 0; nt < 4; nt++) {
        int r = WC + nt * 16 + c;
        int phys = (ks * 4 + q) ^ (r & 7);
        bf[nt] = *(const short8*)&lsB[r * 128 + phys * 8];
      }
#pragma unroll
      for (int mt = 0; mt < 4; mt++)
#pragma unroll
        for (int nt = 0; nt < 4; nt++)
          acc[mt][nt] = MFMA16(af[mt], bf[nt], acc[mt][nt]);
    }
  }

  const float* bp = (m == 0) ? bq : (m == 1) ? bk : bv;
  if (m < 2) {
    short* dst = (short*)(ws + (m == 0 ? Q_OFF : K_OFF));
#pragma unroll
    for (int nt = 0; nt < 4; nt++) {
      int ch = cb + WC + nt * 16 + c;
      float bb = bp[ch];
#pragma unroll
      for (int mt = 0; mt < 4; mt++) {
        int row = R0 + WR + mt * 16 + q * 4;
#pragma unroll
        for (int r = 0; r < 4; r++)
          dst[(row + r) * 256 + ch] = f2b(acc[mt][nt][r] + bb);
      }
    }
  } else {
    short* vt = (short*)(ws + VT_OFF);
    int n = R0 >> 8;
#pragma unroll
    for (int nt = 0; nt < 4; nt++) {
      int ch = cb + WC + nt * 16 + c;
      float bb = bp[ch];
#pragma unroll
      for (int mt = 0; mt < 4; mt++) {
        int j0 = (R0 & 255) + WR + mt * 16 + q * 4;
        short4v s4;
#pragma unroll
        for (int r = 0; r < 4; r++) s4[r] = f2b(acc[mt][nt][r] + bb);
        *(short4v*)&vt[((n * HH + (ch >> 5)) * HDIM + (ch & 31)) * 256 + j0] = s4;
      }
    }
  }
}

// ============================================================================
// K3: attention per (n,h,qq). 2048 blocks x 256 thr. Wave-private P, no barriers.
// ============================================================================
__global__ __launch_bounds__(256) void k3_attn(char* __restrict__ ws)
{
  __shared__ short P[64 * 264];          // 4 waves x 16 rows, ld=264 pad
  int bx = blockIdx.x, tid = threadIdx.x;
  int n = bx >> 5, h = (bx >> 2) & 7, qq = bx & 3;
  int w = tid >> 6, l = tid & 63, q = l >> 4, c = l & 15;
  const short* qs  = (const short*)(ws + Q_OFF);
  const short* kks = (const short*)(ws + K_OFF);
  const short* vt  = (const short*)(ws + VT_OFF);
  const float* pbp = (const float*)(ws + PB_OFF) + h * 65536;
  short* os = (short*)(ws + O_OFF);
  const float scale = 0.17677669529663687f;   // 1/sqrt(32)
  int i0 = qq * 64 + w * 16;             // this wave's 16 query rows
  short8 aq = *(const short8*)&qs[(n * 256 + i0 + c) * 256 + h * 32 + q * 8];
  float4v s[16];
#pragma unroll
  for (int jt = 0; jt < 16; jt++) {
    short8 bk8 = *(const short8*)&kks[(n * 256 + jt * 16 + c) * 256 + h * 32 + q * 8];
    s[jt] = MFMA16(aq, bk8, zero4());
  }
#pragma unroll
  for (int jt = 0; jt < 16; jt++) {
#pragma unroll
    for (int r = 0; r < 4; r++) {
      float pbv = pbp[(i0 + q * 4 + r) * 256 + jt * 16 + c];
      s[jt][r] = __builtin_fmaf(s[jt][r], scale, pbv);
    }
  }
  float inv[4];
#pragma unroll
  for (int r = 0; r < 4; r++) {
    float m = s[0][r];
#pragma unroll
    for (int jt = 1; jt < 16; jt++) m = fmaxf(m, s[jt][r]);
    m = fmaxf(m, __shfl_xor(m, 1, 64));
    m = fmaxf(m, __shfl_xor(m, 2, 64));
    m = fmaxf(m, __shfl_xor(m, 4, 64));
    m = fmaxf(m, __shfl_xor(m, 8, 64));
    float rs = 0.f;
#pragma unroll
    for (int jt = 0; jt < 16; jt++) {
      float p = __expf(s[jt][r] - m);
      s[jt][r] = p;
      rs += p;
    }
    rs += __shfl_xor(rs, 1, 64);
    rs += __shfl_xor(rs, 2, 64);
    rs += __shfl_xor(rs, 4, 64);
    rs += __shfl_xor(rs, 8, 64);
    inv[r] = 1.f / rs;
  }
#pragma unroll
  for (int jt = 0; jt < 16; jt++)
#pragma unroll
    for (int r = 0; r < 4; r++)
      P[(w * 16 + q * 4 + r) * 264 + jt * 16 + c] = f2b(s[jt][r]);
  float4v o0 = zero4(), o1 = zero4();
#pragma unroll
  for (int kk = 0; kk < 8; kk++) {
    short8 ap = *(const short8*)&P[(w * 16 + c) * 264 + kk * 32 + q * 8];
    short8 b0 = *(const short8*)&vt[((n * HH + h) * HDIM + c) * 256 + kk * 32 + q * 8];
    short8 b1 = *(const short8*)&vt[((n * HH + h) * HDIM + 16 + c) * 256 + kk * 32 + q * 8];
    o0 = MFMA16(ap, b0, o0);
    o1 = MFMA16(ap, b1, o1);
  }
#pragma unroll
  for (int r = 0; r < 4; r++) {
    os[(n * 256 + i0 + q * 4 + r) * 256 + h * 32 + c]      = f2b(o0[r] * inv[r]);
    os[(n * 256 + i0 + q * 4 + r) * 256 + h * 32 + 16 + c] = f2b(o1[r] * inv[r]);
  }
}

// ============================================================================
// K4: out-proj + bias + residual + LayerNorm, LDS-staged GEMM.
// grid 256 (64 rows each); wave = 16 rows x 256 cols so LN is wave-local.
// ============================================================================
__global__ __launch_bounds__(256) void k4_out(
    const float* __restrict__ msa, const float* __restrict__ bo,
    const float* __restrict__ gamma, const float* __restrict__ beta,
    const char* __restrict__ ws, float* __restrict__ out)
{
  __shared__ __align__(16) short lsA[64 * 128];
  __shared__ __align__(16) short lsB[256 * 128];
  int bx = blockIdx.x, tid = threadIdx.x;
  int w = tid >> 6, l = tid & 63, q = l >> 4, c = l & 15;
  int R0 = bx * 64;
  const short* osrc = (const short*)(ws + O_OFF);
  const short* wto  = (const short*)(ws + WT_OFF) + 3 * 65536;
  float4v acc[16];
#pragma unroll
  for (int nt = 0; nt < 16; nt++) acc[nt] = zero4();

#pragma unroll 1
  for (int kk = 0; kk < 2; kk++) {
    if (kk) __syncthreads();
#pragma unroll
    for (int i = 0; i < 4; i++) {        // A: 64 rows x 16 chunks
      int ci = i * 256 + tid;
      int r = ci >> 4, pos = ci & 15;
      int kc = pos ^ (r & 7);
      ld_lds16(&osrc[(R0 + r) * 256 + kk * 128 + kc * 8], &lsA[ci * 8]);
    }
#pragma unroll
    for (int i = 0; i < 16; i++) {       // B: 256 ch x 16 chunks
      int ci = i * 256 + tid;
      int r = ci >> 4, pos = ci & 15;
      int kc = pos ^ (r & 7);
      ld_lds16(&wto[r * 256 + kk * 128 + kc * 8], &lsB[ci * 8]);
    }
    WAIT_VM0();
    __syncthreads();
#pragma unroll
    for (int ks = 0; ks < 4; ks++) {
      int rA = w * 16 + c;
      int physA = (ks * 4 + q) ^ (rA & 7);
      short8 af = *(const short8*)&lsA[rA * 128 + physA * 8];
#pragma unroll
      for (int nt = 0; nt < 16; nt++) {
        int r = nt * 16 + c;
        int phys = (ks * 4 + q) ^ (r & 7);
        short8 bf = *(const short8*)&lsB[r * 128 + phys * 8];
        acc[nt] = MFMA16(af, bf, acc[nt]);
      }
    }
  }

  int r0 = R0 + w * 16;
  float s1[4] = {0, 0, 0, 0}, s2[4] = {0, 0, 0, 0};
#pragma unroll
  for (int nt = 0; nt < 16; nt++) {
    float bb = bo[nt * 16 + c];
#pragma unroll
    for (int r = 0; r < 4; r++) {
      float x = acc[nt][r] + bb + msa[(r0 + q * 4 + r) * 256 + nt * 16 + c];
      acc[nt][r] = x;
      s1[r] += x;
      s2[r] = __builtin_fmaf(x, x, s2[r]);
    }
  }
  float mu[4], rsd[4];
#pragma unroll
  for (int r = 0; r < 4; r++) {
    float a = s1[r], b = s2[r];
    a += __shfl_xor(a, 1, 64); b += __shfl_xor(b, 1, 64);
    a += __shfl_xor(a, 2, 64); b += __shfl_xor(b, 2, 64);
    a += __shfl_xor(a, 4, 64); b += __shfl_xor(b, 4, 64);
    a += __shfl_xor(a, 8, 64); b += __shfl_xor(b, 8, 64);
    float m = a * (1.f / 256.f);
    float v = __builtin_fmaf(-m, m, b * (1.f / 256.f));
    mu[r] = m;
    rsd[r] = rsqrtf(v + 1e-5f);
  }
#pragma unroll
  for (int nt = 0; nt < 16; nt++) {
    float g = gamma[nt * 16 + c], bt = beta[nt * 16 + c];
#pragma unroll
    for (int r = 0; r < 4; r++)
      out[(r0 + q * 4 + r) * 256 + nt * 16 + c] =
          (acc[nt][r] - mu[r]) * rsd[r] * g + bt;
  }
}

extern "C" void kernel_launch(void* const* d_in, const int* in_sizes, int n_in,
                              void* d_out, int out_size, void* d_ws, size_t ws_size,
                              hipStream_t stream)
{
  const float* msa   = (const float*)d_in[0];
  const float* pair  = (const float*)d_in[1];
  const float* Wq    = (const float*)d_in[2];
  const float* bq    = (const float*)d_in[3];
  const float* Wk    = (const float*)d_in[4];
  const float* bk    = (const float*)d_in[5];
  const float* Wv    = (const float*)d_in[6];
  const float* bv    = (const float*)d_in[7];
  const float* Wpb   = (const float*)d_in[8];
  const float* bpb   = (const float*)d_in[9];
  const float* Wo    = (const float*)d_in[10];
  const float* bo    = (const float*)d_in[11];
  const float* gamma = (const float*)d_in[12];
  const float* beta  = (const float*)d_in[13];
  char* ws = (char*)d_ws;
  float* out = (float*)d_out;

  hipLaunchKernelGGL(k1_prep, dim3(1792), dim3(256), 0, stream,
                     msa, pair, Wq, Wk, Wv, Wpb, bpb, Wo, ws);
  hipLaunchKernelGGL(k2_qkv, dim3(768), dim3(256), 0, stream,
                     bq, bk, bv, ws);
  hipLaunchKernelGGL(k3_attn, dim3(2048), dim3(256), 0, stream, ws);
  hipLaunchKernelGGL(k4_out, dim3(256), dim3(256), 0, stream,
                     msa, bo, gamma, beta, ws, out);
}

// Round 4
// 179.377 us; speedup vs baseline: 1.3518x; 1.0452x over previous
//
#include <hip/hip_runtime.h>

// Problem constants
#define NSEQ 64
#define LL   256
#define DD   256
#define HH   8
#define HDIM 32

typedef short short8  __attribute__((ext_vector_type(8)));
typedef short short4v __attribute__((ext_vector_type(4)));
typedef float float4v __attribute__((ext_vector_type(4)));

#define MFMA16(a,b,c) __builtin_amdgcn_mfma_f32_16x16x32_bf16((a),(b),(c),0,0,0)

__device__ __forceinline__ float4v zero4() {
  float4v z;
  z[0] = 0.f; z[1] = 0.f; z[2] = 0.f; z[3] = 0.f;
  return z;
}

__device__ __forceinline__ short f2b(float f) {
  unsigned u = __float_as_uint(f);
  u = (u + 0x7fffu + ((u >> 16) & 1u)) >> 16;   // RNE
  return (short)u;
}

__device__ __forceinline__ float b2f(short s) {
  return __uint_as_float(((unsigned)(unsigned short)s) << 16);
}

__device__ __forceinline__ short8 cvt8(const float* p) {
  float4 a = *(const float4*)p;
  float4 b = *(const float4*)(p + 4);
  short8 r;
  r[0] = f2b(a.x); r[1] = f2b(a.y); r[2] = f2b(a.z); r[3] = f2b(a.w);
  r[4] = f2b(b.x); r[5] = f2b(b.y); r[6] = f2b(b.z); r[7] = f2b(b.w);
  return r;
}

// async global->LDS, 16B per lane. LDS dest must be wave-uniform-base + lane*16.
__device__ __forceinline__ void ld_lds16(const void* g, void* l) {
  __builtin_amdgcn_global_load_lds(
      (const __attribute__((address_space(1))) unsigned int*)g,
      (__attribute__((address_space(3))) unsigned int*)l, 16, 0, 0);
}
#define WAIT_VM0() __builtin_amdgcn_s_waitcnt(0x0F70)   // vmcnt(0) only

// ---- workspace layout (bytes); total ~34.5 MB (MSA16 and O share) ----
#define WT_OFF    0                            // 4 x 256x256 bf16 (Wq^T,Wk^T,Wv^T,Wo^T) [ch][k]
#define PB_OFF    (4*65536*2)                  // pb bf16 [h][i][j] (1MB) + fragments (1MB)
#define PBF_OFF   (PB_OFF + 8*65536*2)         // pb bf16 fragments [h][it][jt][lane][4]
#define Q_OFF     (PB_OFF + 8*65536*4)         // per-head q_h[n][h][i][hd] bf16
#define K_OFF     (Q_OFF  + 16384*256*2)       // per-head k_h[n][h][j][hd] bf16
#define VT_OFF    (K_OFF  + 16384*256*2)       // [n][h][hd][j] bf16
#define MSA16_OFF (VT_OFF + 16384*256*2)       // 16384x256 bf16 (dead after k2)
#define O_OFF     MSA16_OFF                    // k3 output overlays MSA16

// ============================================================================
// K1: pb GEMM (256) + weight transpose (1024) + msa->bf16 (512) = 1792 blocks
// ============================================================================
__global__ __launch_bounds__(256) void k1_prep(
    const float* __restrict__ msa,  const float* __restrict__ pair,
    const float* __restrict__ Wq,   const float* __restrict__ Wk,
    const float* __restrict__ Wv,   const float* __restrict__ Wpb,
    const float* __restrict__ bpb,  const float* __restrict__ Wo,
    char* __restrict__ ws)
{
  __shared__ short ldsWt[16 * 136];   // Wpb^T bf16, rows 8..15 zero, ld=136 (pad)
  int bx = blockIdx.x, tid = threadIdx.x;
  if (bx < 256) {
    short* pb16 = (short*)(ws + PB_OFF);
    for (int i = tid; i < 16 * 136; i += 256) ldsWt[i] = 0;
    __syncthreads();
    {
      float4 wv4 = *(const float4*)&Wpb[tid * 4];
      int kk = (tid * 4) >> 3, n0 = (tid * 4) & 7;
      ldsWt[(n0 + 0) * 136 + kk] = f2b(wv4.x);
      ldsWt[(n0 + 1) * 136 + kk] = f2b(wv4.y);
      ldsWt[(n0 + 2) * 136 + kk] = f2b(wv4.z);
      ldsWt[(n0 + 3) * 136 + kk] = f2b(wv4.w);
    }
    __syncthreads();
    int w = tid >> 6, l = tid & 63, q = l >> 4, c = l & 15;
    int base = bx * 256 + w * 64;          // block bx covers pair row i=bx, all j
    float bias = bpb[c & 7];
    short8 bf[4];
#pragma unroll
    for (int ks = 0; ks < 4; ks++)
      bf[ks] = *(const short8*)&ldsWt[c * 136 + ks * 32 + q * 8];
    float4v acc[4];
#pragma unroll
    for (int mt = 0; mt < 4; mt++) acc[mt] = zero4();
#pragma unroll
    for (int ks = 0; ks < 4; ks++) {
#pragma unroll
      for (int mt = 0; mt < 4; mt++) {
        short8 af = cvt8(&pair[(base + mt * 16 + c) * 128 + ks * 32 + q * 8]);
        acc[mt] = MFMA16(af, bf[ks], acc[mt]);
      }
    }
    if (c < 8) {
#pragma unroll
      for (int mt = 0; mt < 4; mt++) {
        short4v o;
#pragma unroll
        for (int r = 0; r < 4; r++) o[r] = f2b(acc[mt][r] + bias);
        *(short4v*)&pb16[c * 65536 + base + mt * 16 + q * 4] = o;
      }
    }
  } else if (bx < 1280) {
    // weight transpose: wt[n][k] = W[k][n], bf16
    int b2 = bx - 256;
    int mat = b2 >> 8, r = b2 & 255;
    const float* W = (mat == 0) ? Wq : (mat == 1) ? Wk : (mat == 2) ? Wv : Wo;
    short* wt = (short*)(ws + WT_OFF) + mat * 65536;
    wt[tid * 256 + r] = f2b(W[r * 256 + tid]);
  } else {
    // msa -> bf16 row-major
    int b3 = bx - 1280;                 // 0..511, 32 rows each
    const float* src = msa + b3 * 8192;
    short* dst = (short*)(ws + MSA16_OFF) + b3 * 8192;
#pragma unroll
    for (int i = 0; i < 8; i++) {
      int idx = i * 1024 + tid * 4;
      float4 v = *(const float4*)&src[idx];
      short4v s;
      s[0] = f2b(v.x); s[1] = f2b(v.y); s[2] = f2b(v.z); s[3] = f2b(v.w);
      *(short4v*)&dst[idx] = s;
    }
  }
}

// ============================================================================
// K2: QKV GEMM (768 blocks) + pb fragment repack (128 blocks) = 896 blocks.
// GEMM: C[16384x768] = msa16 @ [Wq^T;Wk^T;Wv^T], 128x128 tiles, BK=128,
// LDS-staged via global_load_lds + XOR swizzle. Q/K written per-head packed.
// ============================================================================
__global__ __launch_bounds__(256) void k2_qkv(
    const float* __restrict__ bq, const float* __restrict__ bk,
    const float* __restrict__ bv, char* __restrict__ ws)
{
  __shared__ __align__(16) short lsA[128 * 128];
  __shared__ __align__(16) short lsB[128 * 128];
  int bx = blockIdx.x, tid = threadIdx.x;
  if (bx >= 768) {
    // pb repack: pb16[h][i][j] -> fragments pbf[h][it][jt][lane][reg] (bf16)
    int b = bx - 768;                   // 0..127
    int it16 = b & 15;
    const short* src = (const short*)(ws + PB_OFF) + (b >> 4) * 65536 + it16 * 4096;
    short* pbf = (short*)(ws + PBF_OFF);
    short* lt = lsA;                    // 16 x 264
#pragma unroll
    for (int i2 = 0; i2 < 2; i2++) {
      int idx = i2 * 2048 + tid * 8;
      *(short8*)&lt[(idx >> 8) * 264 + (idx & 255)] = *(const short8*)&src[idx];
    }
    __syncthreads();
#pragma unroll
    for (int i2 = 0; i2 < 4; i2++) {
      int fid = i2 * 256 + tid;
      int jt = fid >> 6, lane = fid & 63;
      int qp = lane >> 4, cp = lane & 15;
      short4v v;
#pragma unroll
      for (int r = 0; r < 4; r++)
        v[r] = lt[(qp * 4 + r) * 264 + jt * 16 + cp];
      *(short4v*)&pbf[((b * 16 + jt) * 64 + lane) * 4] = v;
    }
    return;
  }
  int rt = bx & 127, ct = bx >> 7;       // row-tile, col-tile
  int m = ct >> 1, cb = (ct & 1) * 128;  // matrix, ch base within matrix
  int R0 = rt * 128;
  const short* msa16 = (const short*)(ws + MSA16_OFF);
  const short* wt = (const short*)(ws + WT_OFF) + m * 65536;
  int w = tid >> 6, l = tid & 63, q = l >> 4, c = l & 15;
  int WR = (w & 1) * 64, WC = (w >> 1) * 64;
  float4v acc[4][4];
#pragma unroll
  for (int mt = 0; mt < 4; mt++)
#pragma unroll
    for (int nt = 0; nt < 4; nt++) acc[mt][nt] = zero4();

#pragma unroll 1
  for (int kk = 0; kk < 2; kk++) {
    if (kk) __syncthreads();
#pragma unroll
    for (int i = 0; i < 8; i++) {
      int ci = i * 256 + tid;
      int r = ci >> 4, pos = ci & 15;
      int kc = pos ^ (r & 7);
      ld_lds16(&msa16[(R0 + r) * 256 + kk * 128 + kc * 8], &lsA[ci * 8]);
    }
#pragma unroll
    for (int i = 0; i < 8; i++) {
      int ci = i * 256 + tid;
      int r = ci >> 4, pos = ci & 15;
      int kc = pos ^ (r & 7);
      ld_lds16(&wt[(cb + r) * 256 + kk * 128 + kc * 8], &lsB[ci * 8]);
    }
    WAIT_VM0();
    __syncthreads();
#pragma unroll
    for (int ks = 0; ks < 4; ks++) {
      short8 af[4], bf[4];
#pragma unroll
      for (int mt = 0; mt < 4; mt++) {
        int r = WR + mt * 16 + c;
        int phys = (ks * 4 + q) ^ (r & 7);
        af[mt] = *(const short8*)&lsA[r * 128 + phys * 8];
      }
#pragma unroll
      for (int nt = 0; nt < 4; nt++) {
        int r = WC + nt * 16 + c;
        int phys = (ks * 4 + q) ^ (r & 7);
        bf[nt] = *(const short8*)&lsB[r * 128 + phys * 8];
      }
#pragma unroll
      for (int mt = 0; mt < 4; mt++)
#pragma unroll
        for (int nt = 0; nt < 4; nt++)
          acc[mt][nt] = MFMA16(af[mt], bf[nt], acc[mt][nt]);
    }
  }

  const float* bp = (m == 0) ? bq : (m == 1) ? bk : bv;
  int n = R0 >> 8;
  if (m < 2) {
    // per-head packed: dst[n][h][i][hd]
    short* dst = (short*)(ws + (m == 0 ? Q_OFF : K_OFF));
#pragma unroll
    for (int nt = 0; nt < 4; nt++) {
      int ch = cb + WC + nt * 16 + c;
      float bb = bp[ch];
      int h = ch >> 5, hd = ch & 31;
#pragma unroll
      for (int mt = 0; mt < 4; mt++) {
        int i0 = (R0 & 255) + WR + mt * 16 + q * 4;
#pragma unroll
        for (int r = 0; r < 4; r++)
          dst[((n * HH + h) * 256 + i0 + r) * HDIM + hd] = f2b(acc[mt][nt][r] + bb);
      }
    }
  } else {
    short* vt = (short*)(ws + VT_OFF);
#pragma unroll
    for (int nt = 0; nt < 4; nt++) {
      int ch = cb + WC + nt * 16 + c;
      float bb = bp[ch];
#pragma unroll
      for (int mt = 0; mt < 4; mt++) {
        int j0 = (R0 & 255) + WR + mt * 16 + q * 4;
        short4v s4;
#pragma unroll
        for (int r = 0; r < 4; r++) s4[r] = f2b(acc[mt][nt][r] + bb);
        *(short4v*)&vt[((n * HH + (ch >> 5)) * HDIM + (ch & 31)) * 256 + j0] = s4;
      }
    }
  }
}

// ============================================================================
// K3: attention. 2048 blocks: bx = qq*512 + (n*8+h) so qq-siblings share XCD.
// ============================================================================
__global__ __launch_bounds__(256) void k3_attn(char* __restrict__ ws)
{
  __shared__ short P[64 * 264];          // 4 waves x 16 rows, ld=264 pad
  int bx = blockIdx.x, tid = threadIdx.x;
  int qq = bx >> 9, grp = bx & 511;
  int n = grp >> 3, h = grp & 7;
  int w = tid >> 6, l = tid & 63, q = l >> 4, c = l & 15;
  const short* qh = (const short*)(ws + Q_OFF) + (n * HH + h) * 256 * HDIM;
  const short* kh = (const short*)(ws + K_OFF) + (n * HH + h) * 256 * HDIM;
  const short* vt = (const short*)(ws + VT_OFF) + (n * HH + h) * HDIM * 256;
  const short* pbf = (const short*)(ws + PBF_OFF) + (h * 16 + qq * 4 + w) * 16 * 256;
  short* os = (short*)(ws + O_OFF);
  const float scale = 0.17677669529663687f;   // 1/sqrt(32)
  int i0 = qq * 64 + w * 16;             // this wave's 16 query rows
  short8 aq = *(const short8*)&qh[(i0 + c) * HDIM + q * 8];
  float4v s[16];
#pragma unroll
  for (int jt = 0; jt < 16; jt++) {
    short8 bk8 = *(const short8*)&kh[(jt * 16 + c) * HDIM + q * 8];
    s[jt] = MFMA16(aq, bk8, zero4());
  }
  // scale + pair bias from pre-packed fragments (b64 per jt)
#pragma unroll
  for (int jt = 0; jt < 16; jt++) {
    short4v pv = *(const short4v*)&pbf[(jt * 64 + l) * 4];
#pragma unroll
    for (int r = 0; r < 4; r++)
      s[jt][r] = __builtin_fmaf(s[jt][r], scale, b2f(pv[r]));
  }
  float inv[4];
#pragma unroll
  for (int r = 0; r < 4; r++) {
    float m = s[0][r];
#pragma unroll
    for (int jt = 1; jt < 16; jt++) m = fmaxf(m, s[jt][r]);
    m = fmaxf(m, __shfl_xor(m, 1, 64));
    m = fmaxf(m, __shfl_xor(m, 2, 64));
    m = fmaxf(m, __shfl_xor(m, 4, 64));
    m = fmaxf(m, __shfl_xor(m, 8, 64));
    float rs = 0.f;
#pragma unroll
    for (int jt = 0; jt < 16; jt++) {
      float p = __expf(s[jt][r] - m);
      s[jt][r] = p;
      rs += p;
    }
    rs += __shfl_xor(rs, 1, 64);
    rs += __shfl_xor(rs, 2, 64);
    rs += __shfl_xor(rs, 4, 64);
    rs += __shfl_xor(rs, 8, 64);
    inv[r] = 1.f / rs;
  }
#pragma unroll
  for (int jt = 0; jt < 16; jt++)
#pragma unroll
    for (int r = 0; r < 4; r++)
      P[(w * 16 + q * 4 + r) * 264 + jt * 16 + c] = f2b(s[jt][r]);
  float4v o0 = zero4(), o1 = zero4();
#pragma unroll
  for (int kk = 0; kk < 8; kk++) {
    short8 ap = *(const short8*)&P[(w * 16 + c) * 264 + kk * 32 + q * 8];
    short8 b0 = *(const short8*)&vt[c * 256 + kk * 32 + q * 8];
    short8 b1 = *(const short8*)&vt[(16 + c) * 256 + kk * 32 + q * 8];
    o0 = MFMA16(ap, b0, o0);
    o1 = MFMA16(ap, b1, o1);
  }
#pragma unroll
  for (int r = 0; r < 4; r++) {
    os[(n * 256 + i0 + q * 4 + r) * 256 + h * 32 + c]      = f2b(o0[r] * inv[r]);
    os[(n * 256 + i0 + q * 4 + r) * 256 + h * 32 + 16 + c] = f2b(o1[r] * inv[r]);
  }
}

// ============================================================================
// K4: out-proj + bias + residual + LayerNorm, LDS-staged GEMM.
// grid 256 (64 rows each); wave = 16 rows x 256 cols so LN is wave-local.
// ============================================================================
__global__ __launch_bounds__(256) void k4_out(
    const float* __restrict__ msa, const float* __restrict__ bo,
    const float* __restrict__ gamma, const float* __restrict__ beta,
    const char* __restrict__ ws, float* __restrict__ out)
{
  __shared__ __align__(16) short lsA[64 * 128];
  __shared__ __align__(16) short lsB[256 * 128];
  int bx = blockIdx.x, tid = threadIdx.x;
  int w = tid >> 6, l = tid & 63, q = l >> 4, c = l & 15;
  int R0 = bx * 64;
  const short* osrc = (const short*)(ws + O_OFF);
  const short* wto  = (const short*)(ws + WT_OFF) + 3 * 65536;
  float4v acc[16];
#pragma unroll
  for (int nt = 0; nt < 16; nt++) acc[nt] = zero4();

#pragma unroll 1
  for (int kk = 0; kk < 2; kk++) {
    if (kk) __syncthreads();
#pragma unroll
    for (int i = 0; i < 4; i++) {        // A: 64 rows x 16 chunks
      int ci = i * 256 + tid;
      int r = ci >> 4, pos = ci & 15;
      int kc = pos ^ (r & 7);
      ld_lds16(&osrc[(R0 + r) * 256 + kk * 128 + kc * 8], &lsA[ci * 8]);
    }
#pragma unroll
    for (int i = 0; i < 16; i++) {       // B: 256 ch x 16 chunks
      int ci = i * 256 + tid;
      int r = ci >> 4, pos = ci & 15;
      int kc = pos ^ (r & 7);
      ld_lds16(&wto[r * 256 + kk * 128 + kc * 8], &lsB[ci * 8]);
    }
    WAIT_VM0();
    __syncthreads();
#pragma unroll
    for (int ks = 0; ks < 4; ks++) {
      int rA = w * 16 + c;
      int physA = (ks * 4 + q) ^ (rA & 7);
      short8 af = *(const short8*)&lsA[rA * 128 + physA * 8];
#pragma unroll
      for (int nt = 0; nt < 16; nt++) {
        int r = nt * 16 + c;
        int phys = (ks * 4 + q) ^ (r & 7);
        short8 bf = *(const short8*)&lsB[r * 128 + phys * 8];
        acc[nt] = MFMA16(af, bf, acc[nt]);
      }
    }
  }

  int r0 = R0 + w * 16;
  float s1[4] = {0, 0, 0, 0}, s2[4] = {0, 0, 0, 0};
#pragma unroll
  for (int nt = 0; nt < 16; nt++) {
    float bb = bo[nt * 16 + c];
#pragma unroll
    for (int r = 0; r < 4; r++) {
      float x = acc[nt][r] + bb + msa[(r0 + q * 4 + r) * 256 + nt * 16 + c];
      acc[nt][r] = x;
      s1[r] += x;
      s2[r] = __builtin_fmaf(x, x, s2[r]);
    }
  }
  float mu[4], rsd[4];
#pragma unroll
  for (int r = 0; r < 4; r++) {
    float a = s1[r], b = s2[r];
    a += __shfl_xor(a, 1, 64); b += __shfl_xor(b, 1, 64);
    a += __shfl_xor(a, 2, 64); b += __shfl_xor(b, 2, 64);
    a += __shfl_xor(a, 4, 64); b += __shfl_xor(b, 4, 64);
    a += __shfl_xor(a, 8, 64); b += __shfl_xor(b, 8, 64);
    float m = a * (1.f / 256.f);
    float v = __builtin_fmaf(-m, m, b * (1.f / 256.f));
    mu[r] = m;
    rsd[r] = rsqrtf(v + 1e-5f);
  }
#pragma unroll
  for (int nt = 0; nt < 16; nt++) {
    float g = gamma[nt * 16 + c], bt = beta[nt * 16 + c];
#pragma unroll
    for (int r = 0; r < 4; r++)
      out[(r0 + q * 4 + r) * 256 + nt * 16 + c] =
          (acc[nt][r] - mu[r]) * rsd[r] * g + bt;
  }
}

extern "C" void kernel_launch(void* const* d_in, const int* in_sizes, int n_in,
                              void* d_out, int out_size, void* d_ws, size_t ws_size,
                              hipStream_t stream)
{
  const float* msa   = (const float*)d_in[0];
  const float* pair  = (const float*)d_in[1];
  const float* Wq    = (const float*)d_in[2];
  const float* bq    = (const float*)d_in[3];
  const float* Wk    = (const float*)d_in[4];
  const float* bk    = (const float*)d_in[5];
  const float* Wv    = (const float*)d_in[6];
  const float* bv    = (const float*)d_in[7];
  const float* Wpb   = (const float*)d_in[8];
  const float* bpb   = (const float*)d_in[9];
  const float* Wo    = (const float*)d_in[10];
  const float* bo    = (const float*)d_in[11];
  const float* gamma = (const float*)d_in[12];
  const float* beta  = (const float*)d_in[13];
  char* ws = (char*)d_ws;
  float* out = (float*)d_out;

  hipLaunchKernelGGL(k1_prep, dim3(1792), dim3(256), 0, stream,
                     msa, pair, Wq, Wk, Wv, Wpb, bpb, Wo, ws);
  hipLaunchKernelGGL(k2_qkv, dim3(896), dim3(256), 0, stream,
                     bq, bk, bv, ws);
  hipLaunchKernelGGL(k3_attn, dim3(2048), dim3(256), 0, stream, ws);
  hipLaunchKernelGGL(k4_out, dim3(256), dim3(256), 0, stream,
                     msa, bo, gamma, beta, ws, out);
}